// Round 14
// baseline (322.929 us; speedup 1.0000x reference)
//
#include <hip/hip_runtime.h>

// ---------------------------------------------------------------------------
// HAN forward on MI355X — round 14.
//  - projcnt: ONE dispatch, interleaved roles {proj MFMA tiles | edge-count
//    atomics} — count work hides in proj's latency bubbles.
//  - aggscore_mfma: round-13 pipelined gather + s_setprio around MFMA (T5).
//  - final3: beta (2-way softmax) computed inline; beta_kernel dispatch gone.
//  - wconv tiny kernel; single CSR build; scans unchanged.
// ---------------------------------------------------------------------------

typedef __attribute__((ext_vector_type(8))) short bf16x8;
typedef __attribute__((ext_vector_type(4))) float f32x4;
typedef __attribute__((ext_vector_type(8))) unsigned short ushort8;

__device__ __forceinline__ unsigned short f2b(float f) {
  union { float f; unsigned u; } v; v.f = f;
  unsigned r = v.u + 0x7fffu + ((v.u >> 16) & 1u);
  return (unsigned short)(r >> 16);
}
__device__ __forceinline__ float b2f(unsigned short u) {
  union { unsigned u; float f; } v; v.u = ((unsigned)u) << 16;
  return v.f;
}
__device__ __forceinline__ float fast_tanh(float x) {
  x = fminf(fmaxf(x, -15.f), 15.f);
  float t = __expf(2.f * x);
  return 1.f - 2.f / (t + 1.f);
}
__device__ __forceinline__ void gload_lds16(const void* g, void* l) {
  __builtin_amdgcn_global_load_lds(
      (const __attribute__((address_space(1))) unsigned int*)g,
      (__attribute__((address_space(3))) unsigned int*)l, 16, 0, 0);
}

// ---------- wconv: pack W into MFMA B-fragment order ----------
__global__ __launch_bounds__(256) void wconv_kernel(
    const float* __restrict__ Wp, const float* __restrict__ kwm,
    unsigned short* __restrict__ Wpf, unsigned short* __restrict__ Kwf) {
  int t = blockIdx.x * 256 + threadIdx.x;
  const float* W; unsigned short* Wf; int idx;
  if (t < 4096) { W = Wp; Wf = Wpf; idx = t; }
  else if (t < 6144) { W = kwm; Wf = Kwf; idx = t - 4096; }
  else return;
  int lane = idx & 63, nt = (idx >> 6) & 7, kt = idx >> 9;
  int c = lane & 15, ks = lane >> 4;
  int kbase = kt * 32 + ks * 8;
  int col = nt * 16 + c;
  ushort8 o;
#pragma unroll
  for (int j = 0; j < 8; ++j) o[j] = f2b(W[(size_t)(kbase + j) * 128 + col]);
  *(ushort8*)(Wf + (size_t)idx * 8) = o;
}

// ---------- fused: {proj tiles | edge count} ----------
__global__ __launch_bounds__(256) void projcnt_mfma(
    const float* __restrict__ X, const unsigned short* __restrict__ Wf,
    const float* __restrict__ bias,
    const float* __restrict__ as0v, const float* __restrict__ ad0v,
    const float* __restrict__ as1v, const float* __restrict__ ad1v,
    unsigned short* __restrict__ Hb, float* __restrict__ preb,
    const int* __restrict__ e0d, const int* __restrict__ e1d,
    int* __restrict__ deg, int ne, int gproj, int cnt_blks, int n) {
  __shared__ float buf[2][4096];
  const int tid = threadIdx.x;

  // ---- role assignment: interleave proj/count for co-residency ----
  int b = blockIdx.x;
  int small = gproj < cnt_blks ? gproj : cnt_blks;
  int role, id;
  if (b < 2 * small) { role = b & 1; id = b >> 1; }
  else { id = b - 2 * small + small; role = (gproj < cnt_blks) ? 1 : 0; }

  if (role == 1) {   // ---- count role ----
    int e = id * 256 + tid;
    if (e < ne) atomicAdd(&deg[e0d[e]], 1);
    else if (e < 2 * ne) atomicAdd(&deg[200000 + e1d[e - ne]], 1);
    return;
  }

  // ---- proj role (round-12 counted-vmcnt pipeline) ----
  const int wid = tid >> 6, lane = tid & 63;
  const int wm = wid >> 1, wn = wid & 1;
  const int row0 = id * 64;
  const int r = lane & 15, ks = lane >> 4;

  f32x4 acc[2][4] = {};
  const unsigned short* bptr = Wf + ((size_t)(wn * 4) * 64 + lane) * 8;
  bf16x8 Br0[8], Br1[8];

#define VMWAIT(N) asm volatile("s_waitcnt vmcnt(" #N ")" ::: "memory")
#define SBAR()                                                                 \
  {                                                                            \
    __builtin_amdgcn_sched_barrier(0);                                         \
    __builtin_amdgcn_s_barrier();                                              \
    __builtin_amdgcn_sched_barrier(0);                                         \
  }

#define STAGE(bb, s)                                                           \
  {                                                                            \
    _Pragma("unroll")                                                          \
    for (int i = 0; i < 4; ++i) {                                              \
      int rloc = wid * 16 + i * 4 + ks;                                        \
      int grow = row0 + rloc;                                                  \
      grow = grow < n ? grow : n - 1;                                          \
      const float* src =                                                       \
          X + (size_t)grow * 256 + (s) * 64 + ((r ^ (rloc & 7)) << 2);         \
      gload_lds16(src, &buf[bb][(wid * 16 + i * 4) * 64]);                     \
    }                                                                          \
  }

#define BLOAD(P, s)                                                            \
  {                                                                            \
    _Pragma("unroll")                                                          \
    for (int j = 0; j < 8; ++j)                                                \
      P[j] = *(const bf16x8*)(bptr +                                           \
                (((size_t)(s) * 2 + (j >> 2)) * 8 + (j & 3)) * 512);           \
  }

#define COMPUTE_R(bb, P)                                                       \
  {                                                                            \
    _Pragma("unroll")                                                          \
    for (int kt = 0; kt < 2; ++kt) {                                           \
      bf16x8 a[2];                                                             \
      _Pragma("unroll")                                                        \
      for (int mi = 0; mi < 2; ++mi) {                                         \
        int rr = wm * 32 + mi * 16 + r;                                        \
        const float* lrow = &buf[bb][rr * 64];                                 \
        int c0 = kt * 8 + ks * 2;                                              \
        int sw = rr & 7;                                                       \
        float4 f0 = *(const float4*)(lrow + ((c0 ^ sw) * 4));                  \
        float4 f1 = *(const float4*)(lrow + (((c0 + 1) ^ sw) * 4));            \
        bf16x8 v;                                                              \
        v[0] = (short)f2b(f0.x); v[1] = (short)f2b(f0.y);                      \
        v[2] = (short)f2b(f0.z); v[3] = (short)f2b(f0.w);                      \
        v[4] = (short)f2b(f1.x); v[5] = (short)f2b(f1.y);                      \
        v[6] = (short)f2b(f1.z); v[7] = (short)f2b(f1.w);                      \
        a[mi] = v;                                                             \
      }                                                                        \
      _Pragma("unroll")                                                        \
      for (int ni = 0; ni < 4; ++ni) {                                         \
        acc[0][ni] = __builtin_amdgcn_mfma_f32_16x16x32_bf16(                  \
            a[0], P[kt * 4 + ni], acc[0][ni], 0, 0, 0);                        \
        acc[1][ni] = __builtin_amdgcn_mfma_f32_16x16x32_bf16(                  \
            a[1], P[kt * 4 + ni], acc[1][ni], 0, 0, 0);                        \
      }                                                                        \
    }                                                                          \
  }

  STAGE(0, 0);
  BLOAD(Br0, 0);
  STAGE(1, 1);
  VMWAIT(4); SBAR();
  BLOAD(Br1, 1);
  COMPUTE_R(0, Br0);
  SBAR();
  STAGE(0, 2);
  VMWAIT(4); SBAR();
  BLOAD(Br0, 2);
  COMPUTE_R(1, Br1);
  SBAR();
  STAGE(1, 3);
  VMWAIT(4); SBAR();
  BLOAD(Br1, 3);
  COMPUTE_R(0, Br0);
  SBAR();
  VMWAIT(0); SBAR();
  COMPUTE_R(1, Br1);
  __syncthreads();
#undef STAGE
#undef BLOAD
#undef COMPUTE_R
#undef VMWAIT
#undef SBAR

  unsigned short* ct = (unsigned short*)&buf[0][0];
#pragma unroll
  for (int ni = 0; ni < 4; ++ni) {
    const int col = wn * 64 + ni * 16 + r;
    const float bv = bias[col];
#pragma unroll
    for (int mi = 0; mi < 2; ++mi)
#pragma unroll
      for (int i = 0; i < 4; ++i)
        ct[(wm * 32 + mi * 16 + ks * 4 + i) * 136 + col] = f2b(acc[mi][ni][i] + bv);
  }
  __syncthreads();

  {
    int row = tid >> 2, qq = tid & 3;
    int grow = row0 + row;
    if (grow < n) {
      ushort8* dst = (ushort8*)(Hb + (size_t)grow * 128 + qq * 32);
#pragma unroll
      for (int j = 0; j < 4; ++j) dst[j] = *(ushort8*)&ct[row * 136 + qq * 32 + j * 8];
    }
  }

  const size_t n8 = (size_t)n * 8;
  for (int rh = tid; rh < 512; rh += 256) {
    int row = rh >> 3, head = rh & 7;
    int node = row0 + row;
    if (node < n) {
      float hv[16];
#pragma unroll
      for (int j = 0; j < 16; ++j) hv[j] = b2f(ct[row * 136 + head * 16 + j]);
      float s0 = 0, d0 = 0, s1 = 0, d1 = 0;
      const float* p0 = as0v + head * 16;
      const float* p1 = ad0v + head * 16;
      const float* p2 = as1v + head * 16;
      const float* p3 = ad1v + head * 16;
#pragma unroll
      for (int j = 0; j < 16; ++j) {
        float v = hv[j];
        s0 += v * p0[j]; d0 += v * p1[j];
        s1 += v * p2[j]; d1 += v * p3[j];
      }
      size_t idx = (size_t)node * 8 + head;
      preb[idx] = s0;
      preb[n8 + idx] = d0;
      preb[2 * n8 + idx] = s1;
      preb[3 * n8 + idx] = d1;
    }
  }
}

// ---------- CSR scans ----------
__global__ __launch_bounds__(256) void scan1_kernel(
    const int* __restrict__ deg, int* __restrict__ pre, int* __restrict__ bsum, int m) {
  __shared__ int sd[256];
  int t = threadIdx.x;
  int base = blockIdx.x * 2048 + t * 8;
  int v[8], sum = 0;
#pragma unroll
  for (int j = 0; j < 8; ++j) {
    v[j] = (base + j < m) ? deg[base + j] : 0;
    sum += v[j];
  }
  sd[t] = sum;
  __syncthreads();
  for (int off = 1; off < 256; off <<= 1) {
    int x = (t >= off) ? sd[t - off] : 0;
    __syncthreads();
    if (t >= off) sd[t] += x;
    __syncthreads();
  }
  if (t == 255) bsum[blockIdx.x] = sd[255];
  int run = sd[t] - sum;
#pragma unroll
  for (int j = 0; j < 8; ++j) {
    if (base + j < m) pre[base + j] = run;
    run += v[j];
  }
}

__global__ __launch_bounds__(256) void scan2_kernel(int* __restrict__ bsum, int nb) {
  __shared__ int sd[256];
  int t = threadIdx.x;
  int v = (t < nb) ? bsum[t] : 0;
  sd[t] = v;
  __syncthreads();
  for (int off = 1; off < 256; off <<= 1) {
    int x = (t >= off) ? sd[t - off] : 0;
    __syncthreads();
    if (t >= off) sd[t] += x;
    __syncthreads();
  }
  if (t < nb) bsum[t] = sd[t] - v;
}

__global__ void scan3_kernel(int* __restrict__ pre, const int* __restrict__ bsum, int m, int total) {
  int i = blockIdx.x * 256 + threadIdx.x;
  if (i < m) pre[i] += bsum[i >> 11];
  if (i == m) pre[m] = total;
}

__global__ void fill2_kernel(const int* __restrict__ e0s, const int* __restrict__ e0d,
                             const int* __restrict__ e1s, const int* __restrict__ e1d,
                             const int* __restrict__ pre, int* __restrict__ cur,
                             int* __restrict__ csr, int ne, int n) {
  int e = blockIdx.x * 256 + threadIdx.x;
  int s, idx;
  if (e < ne) { idx = e0d[e]; s = e0s[e]; }
  else if (e < 2 * ne) { idx = n + e1d[e - ne]; s = e1s[e - ne]; }
  else return;
  int slot = pre[idx] + atomicAdd(&cur[idx], 1);
  csr[slot] = s;
}

// ---------- FUSED: pipelined gather -> LDS -> score MFMA || lin_w ----------
__global__ __launch_bounds__(512) void aggscore_mfma(
    const int* __restrict__ pre, const int* __restrict__ csr,
    const unsigned short* __restrict__ Hb, const float* __restrict__ preb,
    const unsigned short* __restrict__ Kf, const float* __restrict__ kb,
    const float* __restrict__ q, const float* __restrict__ lw,
    float* __restrict__ pout, float* __restrict__ sb, int n) {
  __shared__ unsigned short at[16384];
  __shared__ float red[8];
  const int rel = blockIdx.y;
  const int tid = threadIdx.x;
  const int row0 = blockIdx.x * 128;
  const size_t n8 = (size_t)n * 8;
  const float* a_s = preb + (size_t)(2 * rel) * n8;
  const float* a_d = preb + (size_t)(2 * rel + 1) * n8;

  // ---- Phase 1: pipelined gather ----
  {
    const int lane8 = tid & 7;
    const int nsub = tid >> 3;
#pragma unroll
    for (int it = 0; it < 2; ++it) {
      int row = it * 64 + nsub;
      int node = row0 + row;
      float s = 0.f;
      float acc[16] = {};
      if (node < n) {
        int beg = pre[rel * n + node];
        int cnt = pre[rel * n + node + 1] - beg;
        if (cnt > 0) {
          float ad = a_d[(size_t)node * 8 + lane8];
          int i0 = csr[beg];
          int i1 = csr[beg + (cnt > 1 ? 1 : 0)];
          float as0 = a_s[(size_t)i0 * 8 + lane8];
          float as1 = a_s[(size_t)i1 * 8 + lane8];
          const ushort8* hp0 = (const ushort8*)(Hb + (size_t)i0 * 128 + lane8 * 16);
          const ushort8* hp1 = (const ushort8*)(Hb + (size_t)i1 * 128 + lane8 * 16);
          ushort8 h0a = hp0[0], h0b = hp0[1];
          ushort8 h1a = hp1[0], h1b = hp1[1];
          for (int k = 0; k < cnt; k += 2) {
            int c2 = (k + 2 < cnt) ? k + 2 : cnt - 1;
            int c3 = (k + 3 < cnt) ? k + 3 : cnt - 1;
            int j0 = csr[beg + c2], j1 = csr[beg + c3];
            float nas0 = a_s[(size_t)j0 * 8 + lane8];
            float nas1 = a_s[(size_t)j1 * 8 + lane8];
            const ushort8* np0 = (const ushort8*)(Hb + (size_t)j0 * 128 + lane8 * 16);
            const ushort8* np1 = (const ushort8*)(Hb + (size_t)j1 * 128 + lane8 * 16);
            ushort8 nh0a = np0[0], nh0b = np0[1];
            ushort8 nh1a = np1[0], nh1b = np1[1];
            float al0 = as0 + ad, al1 = as1 + ad;
            al0 = (al0 >= 0.f) ? al0 : 0.2f * al0;
            al1 = (al1 >= 0.f) ? al1 : 0.2f * al1;
            float p0 = __expf(al0);
            float p1 = (k + 1 < cnt) ? __expf(al1) : 0.f;
            s += p0 + p1;
#pragma unroll
            for (int j = 0; j < 8; ++j) {
              acc[j]     += p0 * b2f(h0a[j]) + p1 * b2f(h1a[j]);
              acc[8 + j] += p0 * b2f(h0b[j]) + p1 * b2f(h1b[j]);
            }
            as0 = nas0; as1 = nas1;
            h0a = nh0a; h0b = nh0b; h1a = nh1a; h1b = nh1b;
          }
        }
      }
      float inv = 1.f / (s + 1e-16f);
      ushort8 o0, o1;
#pragma unroll
      for (int j = 0; j < 8; ++j) {
        o0[j] = f2b(fmaxf(acc[j] * inv, 0.f));
        o1[j] = f2b(fmaxf(acc[8 + j] * inv, 0.f));
      }
      int sw = row & 7;
      *(ushort8*)&at[row * 128 + (((lane8 * 2) ^ sw) * 8)] = o0;
      *(ushort8*)&at[row * 128 + (((lane8 * 2 + 1) ^ sw) * 8)] = o1;
    }
  }
  __syncthreads();

  // ---- Phase 2: waves 0-3 score MFMA + tanh || waves 4-7 lin_w proj ----
  const int wid = tid >> 6;
  float part = 0.f;
  if (wid < 4) {
    const int lane = tid & 63;
    const int wm = wid >> 1, wn = wid & 1;
    const int r = lane & 15, ks = lane >> 4;
    f32x4 acc[4][4] = {};
    const unsigned short* bptr = Kf + ((size_t)(wn * 4) * 64 + lane) * 8;
    __builtin_amdgcn_s_setprio(1);
#pragma unroll
    for (int kt = 0; kt < 4; ++kt) {
      bf16x8 a[4], b[4];
#pragma unroll
      for (int mi = 0; mi < 4; ++mi) {
        int row = wm * 64 + mi * 16 + r;
        a[mi] = *(const bf16x8*)&at[row * 128 + (((kt * 4 + ks) ^ (row & 7)) * 8)];
      }
#pragma unroll
      for (int ni = 0; ni < 4; ++ni)
        b[ni] = *(const bf16x8*)(bptr + ((size_t)kt * 8 + ni) * 512);
#pragma unroll
      for (int mi = 0; mi < 4; ++mi)
#pragma unroll
        for (int ni = 0; ni < 4; ++ni)
          acc[mi][ni] = __builtin_amdgcn_mfma_f32_16x16x32_bf16(a[mi], b[ni], acc[mi][ni], 0, 0, 0);
    }
    __builtin_amdgcn_s_setprio(0);
#pragma unroll
    for (int ni = 0; ni < 4; ++ni) {
      const int col = wn * 64 + ni * 16 + r;
      const float kbv = kb[col], qv = q[col];
#pragma unroll
      for (int mi = 0; mi < 4; ++mi) {
#pragma unroll
        for (int i = 0; i < 4; ++i) {
          int row = row0 + wm * 64 + mi * 16 + ks * 4 + i;
          if (row < n) part += fast_tanh(acc[mi][ni][i] + kbv) * qv;
        }
      }
    }
  } else if (tid < 384) {
    int t2 = tid - 256;
    int node = row0 + t2;
    if (node < n) {
      float p0 = 0.f, p1 = 0.f, p2 = 0.f;
      int s = t2 & 7;
#pragma unroll
      for (int c = 0; c < 16; ++c) {
        const unsigned short* rp = &at[t2 * 128 + ((c ^ s) * 8)];
#pragma unroll
        for (int j = 0; j < 8; ++j) {
          float v = b2f(rp[j]);
          const float* w = lw + (size_t)(c * 8 + j) * 3;
          p0 += v * w[0]; p1 += v * w[1]; p2 += v * w[2];
        }
      }
      float4 o = make_float4(p0, p1, p2, 0.f);
      *(float4*)(pout + (size_t)node * 8 + rel * 4) = o;
    }
  }
#pragma unroll
  for (int off = 32; off > 0; off >>= 1) part += __shfl_down(part, off, 64);
  if ((tid & 63) == 0) red[wid] = part;
  __syncthreads();
  if (tid == 0) {
    float t = 0.f;
#pragma unroll
    for (int w = 0; w < 8; ++w) t += red[w];
    atomicAdd(&sb[rel], t);
  }
}

// ---------- final: beta inline + weighted combine ----------
__global__ __launch_bounds__(256) void final3_kernel(
    const float* __restrict__ pout, const float* __restrict__ sb,
    const float* __restrict__ lb, float* __restrict__ out, int n, float invn) {
  int node = blockIdx.x * 256 + threadIdx.x;
  if (node >= n) return;
  float s0 = sb[0] * invn, s1 = sb[1] * invn;
  float m = fmaxf(s0, s1);
  float e0 = __expf(s0 - m), e1 = __expf(s1 - m);
  float d = e0 + e1;
  float b0 = e0 / d, b1 = e1 / d;
  const float4* p = (const float4*)(pout + (size_t)node * 8);
  float4 pa = p[0], pb = p[1];
  float* dd = out + (size_t)node * 3;
  dd[0] = b0 * pa.x + b1 * pb.x + lb[0];
  dd[1] = b0 * pa.y + b1 * pb.y + lb[1];
  dd[2] = b0 * pa.z + b1 * pb.z + lb[2];
}

extern "C" void kernel_launch(void* const* d_in, const int* in_sizes, int n_in,
                              void* d_out, int out_size, void* d_ws, size_t ws_size,
                              hipStream_t stream) {
  const float* x   = (const float*)d_in[0];
  const float* Wp  = (const float*)d_in[1];
  const float* bp  = (const float*)d_in[2];
  const float* as0 = (const float*)d_in[3];
  const float* ad0 = (const float*)d_in[4];
  const float* as1 = (const float*)d_in[5];
  const float* ad1 = (const float*)d_in[6];
  const float* q   = (const float*)d_in[7];
  const float* kw  = (const float*)d_in[8];
  const float* kb  = (const float*)d_in[9];
  const float* lw  = (const float*)d_in[10];
  const float* lb  = (const float*)d_in[11];
  const int* e0s = (const int*)d_in[12];
  const int* e0d = (const int*)d_in[13];
  const int* e1s = (const int*)d_in[14];
  const int* e1d = (const int*)d_in[15];
  const int n  = in_sizes[0] / 256;
  const int ne = in_sizes[12];
  float* out = (float*)d_out;

  char* ws = (char*)d_ws;
  size_t off = 0;
  auto alloc = [&](size_t b) -> char* {
    char* p = ws + off;
    off = (off + b + 255) & ~(size_t)255;
    return p;
  };
  unsigned short* h    = (unsigned short*)alloc((size_t)n * 128 * 2);
  float* preb = (float*)alloc((size_t)4 * n * 8 * 4);
  float* pout = (float*)alloc((size_t)n * 8 * 4);
  int* pre    = (int*)alloc((size_t)(2 * n + 1) * 4);
  int* csr    = (int*)alloc((size_t)2 * ne * 4);
  int* deg    = (int*)alloc(((size_t)4 * n + 4) * 4);   // deg(2n) | cur(2n) | sb(4)
  int* cur    = deg + 2 * n;
  float* sb   = (float*)(deg + 4 * n);
  int* bsum   = (int*)alloc(256 * 4);
  unsigned short* Wpf = (unsigned short*)alloc((size_t)4096 * 8 * 2);
  unsigned short* Kwf = (unsigned short*)alloc((size_t)2048 * 8 * 2);

  const int m = 2 * n;
  const int nblk_scan = (m + 2047) / 2048;
  const int gproj = (n + 63) / 64;
  const int cnt_blks = (2 * ne + 255) / 256;

  hipMemsetAsync(deg, 0, ((size_t)4 * n + 4) * 4, stream);
  hipLaunchKernelGGL(wconv_kernel, dim3(24), dim3(256), 0, stream, Wp, kw, Wpf, Kwf);

  hipLaunchKernelGGL(projcnt_mfma, dim3(gproj + cnt_blks), dim3(256), 0, stream,
                     x, Wpf, bp, as0, ad0, as1, ad1, h, preb,
                     e0d, e1d, deg, ne, gproj, cnt_blks, n);

  hipLaunchKernelGGL(scan1_kernel, dim3(nblk_scan), dim3(256), 0, stream, deg, pre, bsum, m);
  hipLaunchKernelGGL(scan2_kernel, dim3(1), dim3(256), 0, stream, bsum, nblk_scan);
  hipLaunchKernelGGL(scan3_kernel, dim3((m + 1 + 255) / 256), dim3(256), 0, stream,
                     pre, bsum, m, 2 * ne);
  hipLaunchKernelGGL(fill2_kernel, dim3((2 * ne + 255) / 256), dim3(256), 0, stream,
                     e0s, e0d, e1s, e1d, pre, cur, csr, ne, n);

  hipLaunchKernelGGL(aggscore_mfma, dim3((n + 127) / 128, 2), dim3(512), 0, stream,
                     pre, csr, h, preb, Kwf, kb, q, lw, pout, sb, n);
  hipLaunchKernelGGL(final3_kernel, dim3((n + 255) / 256), dim3(256), 0, stream,
                     pout, sb, lb, out, n, 1.0f / n);
}

// Round 15
// 295.427 us; speedup vs baseline: 1.0931x; 1.0931x over previous
//
#include <hip/hip_runtime.h>

// ---------------------------------------------------------------------------
// HAN forward on MI355X — round 15 (consolidation: revert round-14 fusion).
//  - prep_lite {edge count | W pack} (separate dispatch — fusion regressed).
//  - proj_mfma: round-12/13 counted-vmcnt double-buffered pipeline.
//  - aggscore_mfma: round-13 pipelined gather + T5 setprio around MFMA.
//  - final3: beta (2-way softmax) inline; beta_kernel dispatch removed.
// ---------------------------------------------------------------------------

typedef __attribute__((ext_vector_type(8))) short bf16x8;
typedef __attribute__((ext_vector_type(4))) float f32x4;
typedef __attribute__((ext_vector_type(8))) unsigned short ushort8;

__device__ __forceinline__ unsigned short f2b(float f) {
  union { float f; unsigned u; } v; v.f = f;
  unsigned r = v.u + 0x7fffu + ((v.u >> 16) & 1u);
  return (unsigned short)(r >> 16);
}
__device__ __forceinline__ float b2f(unsigned short u) {
  union { unsigned u; float f; } v; v.u = ((unsigned)u) << 16;
  return v.f;
}
__device__ __forceinline__ float fast_tanh(float x) {
  x = fminf(fmaxf(x, -15.f), 15.f);
  float t = __expf(2.f * x);
  return 1.f - 2.f / (t + 1.f);
}
__device__ __forceinline__ void gload_lds16(const void* g, void* l) {
  __builtin_amdgcn_global_load_lds(
      (const __attribute__((address_space(1))) unsigned int*)g,
      (__attribute__((address_space(3))) unsigned int*)l, 16, 0, 0);
}

// ---------- prep_lite: edge count | W fragment pack ----------
__global__ __launch_bounds__(256) void prep_lite(
    const int* __restrict__ e0d, const int* __restrict__ e1d,
    int* __restrict__ deg, int ne, int n,
    const float* __restrict__ Wp, const float* __restrict__ kwm,
    unsigned short* __restrict__ Wpf, unsigned short* __restrict__ Kwf) {
  const int tid = threadIdx.x;
  int b = blockIdx.x;
  const int cb = (2 * ne + 255) >> 8;
  if (b < cb) {
    int e = b * 256 + tid;
    if (e < ne) atomicAdd(&deg[e0d[e]], 1);
    else if (e < 2 * ne) atomicAdd(&deg[n + e1d[e - ne]], 1);
    return;
  }
  b -= cb;
  int t = b * 256 + tid;
  const float* W; unsigned short* Wf; int idx;
  if (t < 4096) { W = Wp; Wf = Wpf; idx = t; }
  else if (t < 6144) { W = kwm; Wf = Kwf; idx = t - 4096; }
  else return;
  int lane = idx & 63, nt = (idx >> 6) & 7, kt = idx >> 9;
  int c = lane & 15, ks = lane >> 4;
  int kbase = kt * 32 + ks * 8;
  int col = nt * 16 + c;
  ushort8 o;
#pragma unroll
  for (int j = 0; j < 8; ++j) o[j] = f2b(W[(size_t)(kbase + j) * 128 + col]);
  *(ushort8*)(Wf + (size_t)idx * 8) = o;
}

// ---------- h = X[n,256] @ W + bias (bf16 out) + fused pre-products ----------
__global__ __launch_bounds__(256) void proj_mfma(
    const float* __restrict__ X, const unsigned short* __restrict__ Wf,
    const float* __restrict__ bias,
    const float* __restrict__ as0v, const float* __restrict__ ad0v,
    const float* __restrict__ as1v, const float* __restrict__ ad1v,
    unsigned short* __restrict__ Hb, float* __restrict__ preb, int n) {
  __shared__ float buf[2][4096];
  const int tid = threadIdx.x;
  const int wid = tid >> 6, lane = tid & 63;
  const int wm = wid >> 1, wn = wid & 1;
  const int row0 = blockIdx.x * 64;
  const int r = lane & 15, ks = lane >> 4;

  f32x4 acc[2][4] = {};
  const unsigned short* bptr = Wf + ((size_t)(wn * 4) * 64 + lane) * 8;
  bf16x8 Br0[8], Br1[8];

#define VMWAIT(N) asm volatile("s_waitcnt vmcnt(" #N ")" ::: "memory")
#define SBAR()                                                                 \
  {                                                                            \
    __builtin_amdgcn_sched_barrier(0);                                         \
    __builtin_amdgcn_s_barrier();                                              \
    __builtin_amdgcn_sched_barrier(0);                                         \
  }

#define STAGE(b, s)                                                            \
  {                                                                            \
    _Pragma("unroll")                                                          \
    for (int i = 0; i < 4; ++i) {                                              \
      int rloc = wid * 16 + i * 4 + ks;                                        \
      int grow = row0 + rloc;                                                  \
      grow = grow < n ? grow : n - 1;                                          \
      const float* src =                                                       \
          X + (size_t)grow * 256 + (s) * 64 + ((r ^ (rloc & 7)) << 2);         \
      gload_lds16(src, &buf[b][(wid * 16 + i * 4) * 64]);                      \
    }                                                                          \
  }

#define BLOAD(P, s)                                                            \
  {                                                                            \
    _Pragma("unroll")                                                          \
    for (int j = 0; j < 8; ++j)                                                \
      P[j] = *(const bf16x8*)(bptr +                                           \
                (((size_t)(s) * 2 + (j >> 2)) * 8 + (j & 3)) * 512);           \
  }

#define COMPUTE_R(b, P)                                                        \
  {                                                                            \
    _Pragma("unroll")                                                          \
    for (int kt = 0; kt < 2; ++kt) {                                           \
      bf16x8 a[2];                                                             \
      _Pragma("unroll")                                                        \
      for (int mi = 0; mi < 2; ++mi) {                                         \
        int rr = wm * 32 + mi * 16 + r;                                        \
        const float* lrow = &buf[b][rr * 64];                                  \
        int c0 = kt * 8 + ks * 2;                                              \
        int sw = rr & 7;                                                       \
        float4 f0 = *(const float4*)(lrow + ((c0 ^ sw) * 4));                  \
        float4 f1 = *(const float4*)(lrow + (((c0 + 1) ^ sw) * 4));            \
        bf16x8 v;                                                              \
        v[0] = (short)f2b(f0.x); v[1] = (short)f2b(f0.y);                      \
        v[2] = (short)f2b(f0.z); v[3] = (short)f2b(f0.w);                      \
        v[4] = (short)f2b(f1.x); v[5] = (short)f2b(f1.y);                      \
        v[6] = (short)f2b(f1.z); v[7] = (short)f2b(f1.w);                      \
        a[mi] = v;                                                             \
      }                                                                        \
      _Pragma("unroll")                                                        \
      for (int ni = 0; ni < 4; ++ni) {                                         \
        acc[0][ni] = __builtin_amdgcn_mfma_f32_16x16x32_bf16(                  \
            a[0], P[kt * 4 + ni], acc[0][ni], 0, 0, 0);                        \
        acc[1][ni] = __builtin_amdgcn_mfma_f32_16x16x32_bf16(                  \
            a[1], P[kt * 4 + ni], acc[1][ni], 0, 0, 0);                        \
      }                                                                        \
    }                                                                          \
  }

  STAGE(0, 0);
  BLOAD(Br0, 0);
  STAGE(1, 1);
  VMWAIT(4); SBAR();
  BLOAD(Br1, 1);
  COMPUTE_R(0, Br0);
  SBAR();
  STAGE(0, 2);
  VMWAIT(4); SBAR();
  BLOAD(Br0, 2);
  COMPUTE_R(1, Br1);
  SBAR();
  STAGE(1, 3);
  VMWAIT(4); SBAR();
  BLOAD(Br1, 3);
  COMPUTE_R(0, Br0);
  SBAR();
  VMWAIT(0); SBAR();
  COMPUTE_R(1, Br1);
  __syncthreads();
#undef STAGE
#undef BLOAD
#undef COMPUTE_R
#undef VMWAIT
#undef SBAR

  unsigned short* ct = (unsigned short*)&buf[0][0];
#pragma unroll
  for (int ni = 0; ni < 4; ++ni) {
    const int col = wn * 64 + ni * 16 + r;
    const float bv = bias[col];
#pragma unroll
    for (int mi = 0; mi < 2; ++mi)
#pragma unroll
      for (int i = 0; i < 4; ++i)
        ct[(wm * 32 + mi * 16 + ks * 4 + i) * 136 + col] = f2b(acc[mi][ni][i] + bv);
  }
  __syncthreads();

  {
    int row = tid >> 2, qq = tid & 3;
    int grow = row0 + row;
    if (grow < n) {
      ushort8* dst = (ushort8*)(Hb + (size_t)grow * 128 + qq * 32);
#pragma unroll
      for (int j = 0; j < 4; ++j) dst[j] = *(ushort8*)&ct[row * 136 + qq * 32 + j * 8];
    }
  }

  const size_t n8 = (size_t)n * 8;
  for (int rh = tid; rh < 512; rh += 256) {
    int row = rh >> 3, head = rh & 7;
    int node = row0 + row;
    if (node < n) {
      float hv[16];
#pragma unroll
      for (int j = 0; j < 16; ++j) hv[j] = b2f(ct[row * 136 + head * 16 + j]);
      float s0 = 0, d0 = 0, s1 = 0, d1 = 0;
      const float* p0 = as0v + head * 16;
      const float* p1 = ad0v + head * 16;
      const float* p2 = as1v + head * 16;
      const float* p3 = ad1v + head * 16;
#pragma unroll
      for (int j = 0; j < 16; ++j) {
        float v = hv[j];
        s0 += v * p0[j]; d0 += v * p1[j];
        s1 += v * p2[j]; d1 += v * p3[j];
      }
      size_t idx = (size_t)node * 8 + head;
      preb[idx] = s0;
      preb[n8 + idx] = d0;
      preb[2 * n8 + idx] = s1;
      preb[3 * n8 + idx] = d1;
    }
  }
}

// ---------- CSR scans ----------
__global__ __launch_bounds__(256) void scan1_kernel(
    const int* __restrict__ deg, int* __restrict__ pre, int* __restrict__ bsum, int m) {
  __shared__ int sd[256];
  int t = threadIdx.x;
  int base = blockIdx.x * 2048 + t * 8;
  int v[8], sum = 0;
#pragma unroll
  for (int j = 0; j < 8; ++j) {
    v[j] = (base + j < m) ? deg[base + j] : 0;
    sum += v[j];
  }
  sd[t] = sum;
  __syncthreads();
  for (int off = 1; off < 256; off <<= 1) {
    int x = (t >= off) ? sd[t - off] : 0;
    __syncthreads();
    if (t >= off) sd[t] += x;
    __syncthreads();
  }
  if (t == 255) bsum[blockIdx.x] = sd[255];
  int run = sd[t] - sum;
#pragma unroll
  for (int j = 0; j < 8; ++j) {
    if (base + j < m) pre[base + j] = run;
    run += v[j];
  }
}

__global__ __launch_bounds__(256) void scan2_kernel(int* __restrict__ bsum, int nb) {
  __shared__ int sd[256];
  int t = threadIdx.x;
  int v = (t < nb) ? bsum[t] : 0;
  sd[t] = v;
  __syncthreads();
  for (int off = 1; off < 256; off <<= 1) {
    int x = (t >= off) ? sd[t - off] : 0;
    __syncthreads();
    if (t >= off) sd[t] += x;
    __syncthreads();
  }
  if (t < nb) bsum[t] = sd[t] - v;
}

__global__ void scan3_kernel(int* __restrict__ pre, const int* __restrict__ bsum, int m, int total) {
  int i = blockIdx.x * 256 + threadIdx.x;
  if (i < m) pre[i] += bsum[i >> 11];
  if (i == m) pre[m] = total;
}

__global__ void fill2_kernel(const int* __restrict__ e0s, const int* __restrict__ e0d,
                             const int* __restrict__ e1s, const int* __restrict__ e1d,
                             const int* __restrict__ pre, int* __restrict__ cur,
                             int* __restrict__ csr, int ne, int n) {
  int e = blockIdx.x * 256 + threadIdx.x;
  int s, idx;
  if (e < ne) { idx = e0d[e]; s = e0s[e]; }
  else if (e < 2 * ne) { idx = n + e1d[e - ne]; s = e1s[e - ne]; }
  else return;
  int slot = pre[idx] + atomicAdd(&cur[idx], 1);
  csr[slot] = s;
}

// ---------- FUSED: pipelined gather -> LDS -> score MFMA || lin_w ----------
__global__ __launch_bounds__(512) void aggscore_mfma(
    const int* __restrict__ pre, const int* __restrict__ csr,
    const unsigned short* __restrict__ Hb, const float* __restrict__ preb,
    const unsigned short* __restrict__ Kf, const float* __restrict__ kb,
    const float* __restrict__ q, const float* __restrict__ lw,
    float* __restrict__ pout, float* __restrict__ sb, int n) {
  __shared__ unsigned short at[16384];
  __shared__ float red[8];
  const int rel = blockIdx.y;
  const int tid = threadIdx.x;
  const int row0 = blockIdx.x * 128;
  const size_t n8 = (size_t)n * 8;
  const float* a_s = preb + (size_t)(2 * rel) * n8;
  const float* a_d = preb + (size_t)(2 * rel + 1) * n8;

  // ---- Phase 1: pipelined gather (8 lanes/node, 2 passes of 64 nodes) ----
  {
    const int lane8 = tid & 7;
    const int nsub = tid >> 3;
#pragma unroll
    for (int it = 0; it < 2; ++it) {
      int row = it * 64 + nsub;
      int node = row0 + row;
      float s = 0.f;
      float acc[16] = {};
      if (node < n) {
        int beg = pre[rel * n + node];
        int cnt = pre[rel * n + node + 1] - beg;
        if (cnt > 0) {
          float ad = a_d[(size_t)node * 8 + lane8];
          int i0 = csr[beg];
          int i1 = csr[beg + (cnt > 1 ? 1 : 0)];
          float as0 = a_s[(size_t)i0 * 8 + lane8];
          float as1 = a_s[(size_t)i1 * 8 + lane8];
          const ushort8* hp0 = (const ushort8*)(Hb + (size_t)i0 * 128 + lane8 * 16);
          const ushort8* hp1 = (const ushort8*)(Hb + (size_t)i1 * 128 + lane8 * 16);
          ushort8 h0a = hp0[0], h0b = hp0[1];
          ushort8 h1a = hp1[0], h1b = hp1[1];
          for (int k = 0; k < cnt; k += 2) {
            int c2 = (k + 2 < cnt) ? k + 2 : cnt - 1;
            int c3 = (k + 3 < cnt) ? k + 3 : cnt - 1;
            int j0 = csr[beg + c2], j1 = csr[beg + c3];
            float nas0 = a_s[(size_t)j0 * 8 + lane8];
            float nas1 = a_s[(size_t)j1 * 8 + lane8];
            const ushort8* np0 = (const ushort8*)(Hb + (size_t)j0 * 128 + lane8 * 16);
            const ushort8* np1 = (const ushort8*)(Hb + (size_t)j1 * 128 + lane8 * 16);
            ushort8 nh0a = np0[0], nh0b = np0[1];
            ushort8 nh1a = np1[0], nh1b = np1[1];
            float al0 = as0 + ad, al1 = as1 + ad;
            al0 = (al0 >= 0.f) ? al0 : 0.2f * al0;
            al1 = (al1 >= 0.f) ? al1 : 0.2f * al1;
            float p0 = __expf(al0);
            float p1 = (k + 1 < cnt) ? __expf(al1) : 0.f;
            s += p0 + p1;
#pragma unroll
            for (int j = 0; j < 8; ++j) {
              acc[j]     += p0 * b2f(h0a[j]) + p1 * b2f(h1a[j]);
              acc[8 + j] += p0 * b2f(h0b[j]) + p1 * b2f(h1b[j]);
            }
            as0 = nas0; as1 = nas1;
            h0a = nh0a; h0b = nh0b; h1a = nh1a; h1b = nh1b;
          }
        }
      }
      float inv = 1.f / (s + 1e-16f);
      ushort8 o0, o1;
#pragma unroll
      for (int j = 0; j < 8; ++j) {
        o0[j] = f2b(fmaxf(acc[j] * inv, 0.f));
        o1[j] = f2b(fmaxf(acc[8 + j] * inv, 0.f));
      }
      int sw = row & 7;
      *(ushort8*)&at[row * 128 + (((lane8 * 2) ^ sw) * 8)] = o0;
      *(ushort8*)&at[row * 128 + (((lane8 * 2 + 1) ^ sw) * 8)] = o1;
    }
  }
  __syncthreads();

  // ---- Phase 2: waves 0-3 score MFMA + tanh || waves 4-7 lin_w proj ----
  const int wid = tid >> 6;
  float part = 0.f;
  if (wid < 4) {
    const int lane = tid & 63;
    const int wm = wid >> 1, wn = wid & 1;
    const int r = lane & 15, ks = lane >> 4;
    f32x4 acc[4][4] = {};
    const unsigned short* bptr = Kf + ((size_t)(wn * 4) * 64 + lane) * 8;
    __builtin_amdgcn_s_setprio(1);
#pragma unroll
    for (int kt = 0; kt < 4; ++kt) {
      bf16x8 a[4], b[4];
#pragma unroll
      for (int mi = 0; mi < 4; ++mi) {
        int row = wm * 64 + mi * 16 + r;
        a[mi] = *(const bf16x8*)&at[row * 128 + (((kt * 4 + ks) ^ (row & 7)) * 8)];
      }
#pragma unroll
      for (int ni = 0; ni < 4; ++ni)
        b[ni] = *(const bf16x8*)(bptr + ((size_t)kt * 8 + ni) * 512);
#pragma unroll
      for (int mi = 0; mi < 4; ++mi)
#pragma unroll
        for (int ni = 0; ni < 4; ++ni)
          acc[mi][ni] = __builtin_amdgcn_mfma_f32_16x16x32_bf16(a[mi], b[ni], acc[mi][ni], 0, 0, 0);
    }
    __builtin_amdgcn_s_setprio(0);
#pragma unroll
    for (int ni = 0; ni < 4; ++ni) {
      const int col = wn * 64 + ni * 16 + r;
      const float kbv = kb[col], qv = q[col];
#pragma unroll
      for (int mi = 0; mi < 4; ++mi) {
#pragma unroll
        for (int i = 0; i < 4; ++i) {
          int row = row0 + wm * 64 + mi * 16 + ks * 4 + i;
          if (row < n) part += fast_tanh(acc[mi][ni][i] + kbv) * qv;
        }
      }
    }
  } else if (tid < 384) {
    int t2 = tid - 256;
    int node = row0 + t2;
    if (node < n) {
      float p0 = 0.f, p1 = 0.f, p2 = 0.f;
      int s = t2 & 7;
#pragma unroll
      for (int c = 0; c < 16; ++c) {
        const unsigned short* rp = &at[t2 * 128 + ((c ^ s) * 8)];
#pragma unroll
        for (int j = 0; j < 8; ++j) {
          float v = b2f(rp[j]);
          const float* w = lw + (size_t)(c * 8 + j) * 3;
          p0 += v * w[0]; p1 += v * w[1]; p2 += v * w[2];
        }
      }
      float4 o = make_float4(p0, p1, p2, 0.f);
      *(float4*)(pout + (size_t)node * 8 + rel * 4) = o;
    }
  }
#pragma unroll
  for (int off = 32; off > 0; off >>= 1) part += __shfl_down(part, off, 64);
  if ((tid & 63) == 0) red[wid] = part;
  __syncthreads();
  if (tid == 0) {
    float t = 0.f;
#pragma unroll
    for (int w = 0; w < 8; ++w) t += red[w];
    atomicAdd(&sb[rel], t);
  }
}

// ---------- final: beta inline + weighted combine ----------
__global__ __launch_bounds__(256) void final3_kernel(
    const float* __restrict__ pout, const float* __restrict__ sb,
    const float* __restrict__ lb, float* __restrict__ out, int n, float invn) {
  int node = blockIdx.x * 256 + threadIdx.x;
  if (node >= n) return;
  float s0 = sb[0] * invn, s1 = sb[1] * invn;
  float m = fmaxf(s0, s1);
  float e0 = __expf(s0 - m), e1 = __expf(s1 - m);
  float d = e0 + e1;
  float b0 = e0 / d, b1 = e1 / d;
  const float4* p = (const float4*)(pout + (size_t)node * 8);
  float4 pa = p[0], pb = p[1];
  float* dd = out + (size_t)node * 3;
  dd[0] = b0 * pa.x + b1 * pb.x + lb[0];
  dd[1] = b0 * pa.y + b1 * pb.y + lb[1];
  dd[2] = b0 * pa.z + b1 * pb.z + lb[2];
}

extern "C" void kernel_launch(void* const* d_in, const int* in_sizes, int n_in,
                              void* d_out, int out_size, void* d_ws, size_t ws_size,
                              hipStream_t stream) {
  const float* x   = (const float*)d_in[0];
  const float* Wp  = (const float*)d_in[1];
  const float* bp  = (const float*)d_in[2];
  const float* as0 = (const float*)d_in[3];
  const float* ad0 = (const float*)d_in[4];
  const float* as1 = (const float*)d_in[5];
  const float* ad1 = (const float*)d_in[6];
  const float* q   = (const float*)d_in[7];
  const float* kw  = (const float*)d_in[8];
  const float* kb  = (const float*)d_in[9];
  const float* lw  = (const float*)d_in[10];
  const float* lb  = (const float*)d_in[11];
  const int* e0s = (const int*)d_in[12];
  const int* e0d = (const int*)d_in[13];
  const int* e1s = (const int*)d_in[14];
  const int* e1d = (const int*)d_in[15];
  const int n  = in_sizes[0] / 256;
  const int ne = in_sizes[12];
  float* out = (float*)d_out;

  char* ws = (char*)d_ws;
  size_t off = 0;
  auto alloc = [&](size_t b) -> char* {
    char* p = ws + off;
    off = (off + b + 255) & ~(size_t)255;
    return p;
  };
  unsigned short* h    = (unsigned short*)alloc((size_t)n * 128 * 2);
  float* preb = (float*)alloc((size_t)4 * n * 8 * 4);
  float* pout = (float*)alloc((size_t)n * 8 * 4);
  int* pre    = (int*)alloc((size_t)(2 * n + 1) * 4);
  int* csr    = (int*)alloc((size_t)2 * ne * 4);
  int* deg    = (int*)alloc(((size_t)4 * n + 4) * 4);   // deg(2n) | cur(2n) | sb(4)
  int* cur    = deg + 2 * n;
  float* sb   = (float*)(deg + 4 * n);
  int* bsum   = (int*)alloc(256 * 4);
  unsigned short* Wpf = (unsigned short*)alloc((size_t)4096 * 8 * 2);
  unsigned short* Kwf = (unsigned short*)alloc((size_t)2048 * 8 * 2);

  const int m = 2 * n;
  const int nblk_scan = (m + 2047) / 2048;
  const int cnt_blks = (2 * ne + 255) / 256;

  hipMemsetAsync(deg, 0, ((size_t)4 * n + 4) * 4, stream);
  hipLaunchKernelGGL(prep_lite, dim3(cnt_blks + 24), dim3(256), 0, stream,
                     e0d, e1d, deg, ne, n, Wp, kw, Wpf, Kwf);

  const int gproj = (n + 63) / 64;
  hipLaunchKernelGGL(proj_mfma, dim3(gproj), dim3(256), 0, stream,
                     x, Wpf, bp, as0, ad0, as1, ad1, h, preb, n);

  hipLaunchKernelGGL(scan1_kernel, dim3(nblk_scan), dim3(256), 0, stream, deg, pre, bsum, m);
  hipLaunchKernelGGL(scan2_kernel, dim3(1), dim3(256), 0, stream, bsum, nblk_scan);
  hipLaunchKernelGGL(scan3_kernel, dim3((m + 1 + 255) / 256), dim3(256), 0, stream,
                     pre, bsum, m, 2 * ne);
  hipLaunchKernelGGL(fill2_kernel, dim3((2 * ne + 255) / 256), dim3(256), 0, stream,
                     e0s, e0d, e1s, e1d, pre, cur, csr, ne, n);

  hipLaunchKernelGGL(aggscore_mfma, dim3((n + 127) / 128, 2), dim3(512), 0, stream,
                     pre, csr, h, preb, Kwf, kb, q, lw, pout, sb, n);
  hipLaunchKernelGGL(final3_kernel, dim3((n + 255) / 256), dim3(256), 0, stream,
                     pout, sb, lb, out, n, 1.0f / n);
}